// Round 3
// baseline (134.839 us; speedup 1.0000x reference)
//
#include <hip/hip_runtime.h>
#include <hip/hip_bf16.h>

// Problem constants
#define NB   4      // batch
#define CCH  3      // channels
#define HW   320    // height == width
#define KS   5      // kernel/stride
#define LP   4096   // patches per batch (64*64)
#define KD   75     // c*k*k
#define KP   96     // K padded to multiple of 32 (3 MFMA k-steps)
#define LDK  104    // LDS row stride in elements (208B = 13*16B, aligned, 2-way banks free)

typedef __attribute__((ext_vector_type(4))) float f32x4;
typedef __attribute__((ext_vector_type(8))) short bf16x8;

__device__ __forceinline__ ushort f2bf(float v) {
    __hip_bfloat16 h = __float2bfloat16(v);
    return __builtin_bit_cast(ushort, h);
}

// Kernel 1: per-patch sumsq from x (fp32), block-max over 4 patches, one
// device-scope atomicMax per block onto maxbits[b] (float bits, all >= 0).
__global__ __launch_bounds__(256) void norm_kernel(const float* __restrict__ x,
                                                   unsigned* __restrict__ maxbits) {
    int tid  = threadIdx.x;
    int lane = tid & 63;
    int pid  = blockIdx.x * 4 + (tid >> 6);   // 0..16383 (block spans one batch: 4096%4==0)
    int b    = pid >> 12;
    int pp   = pid & 4095;
    int ph   = pp >> 6, pw = pp & 63;
    const float* xb = x + (size_t)b * (CCH * HW * HW);
    int row0 = ph * KS, col0 = pw * KS;

    float ss = 0.f;
    for (int k = lane; k < KD; k += 64) {
        int c = k / 25, rem = k % 25;
        int ki = rem / 5, kj = rem % 5;
        float v = xb[(c * HW + row0 + ki) * HW + col0 + kj];
        ss += v * v;
    }
    for (int off = 32; off; off >>= 1) ss += __shfl_xor(ss, off, 64);

    __shared__ float sm[4];
    if (lane == 0) sm[tid >> 6] = ss;
    __syncthreads();
    if (tid == 0) {
        float m = fmaxf(fmaxf(sm[0], sm[1]), fmaxf(sm[2], sm[3]));
        atomicMax(maxbits + b, __float_as_uint(m));   // non-negative: bit order == float order
    }
}

// Kernel 2: per batch C = sigmoid((P P^T) / sqrt(max_sumsq)), 128x128 tile per
// block. Patches extracted from x directly into LDS (bf16, zero-padded to KP).
// 4 waves in 2x2; each wave 64x64 = 4x4 fragments of 16x16; K in 3 steps.
// Epilogue stores the TRANSPOSE of each fragment (C is symmetric, and MFMA
// accumulation order makes C[i,j] and C[j,i] bit-identical) -> float4 stores.
__global__ __launch_bounds__(256) void gemm_kernel(const float* __restrict__ x,
                                                   const unsigned* __restrict__ maxbits,
                                                   float* __restrict__ out) {
    __shared__ ushort Asm[128 * LDK];
    __shared__ ushort Bsm[128 * LDK];

    int b  = blockIdx.z;
    int tr = blockIdx.y;   // tile row (p-index / 128)
    int tc = blockIdx.x;   // tile col (q-index / 128)
    int tid = threadIdx.x;
    const float* xb = x + (size_t)b * (CCH * HW * HW);

    // ---- stage A (rows from tile tr) and B (rows from tile tc) out of x ----
    // A 128-patch tile = 2 consecutive ph rows x 64 pw. For each (ph_off,c,ki)
    // the needed x data is one full contiguous row of 320 floats; task t
    // handles 5 floats (one pw cell) of one such row.
    #pragma unroll
    for (int mat = 0; mat < 2; ++mat) {
        ushort* dst = mat ? Bsm : Asm;
        int ph0 = (mat ? tc : tr) * 2;
        for (int t = tid; t < 1920; t += 256) {     // 30 x-rows * 64 pw
            int xr = t >> 6;                        // 0..29
            int pw = t & 63;
            int ph_off = xr / 15, rem = xr % 15;
            int c = rem / 5, ki = rem % 5;
            const float* src = xb + ((size_t)(c * HW) + (size_t)(ph0 + ph_off) * KS + ki) * HW + pw * KS;
            ushort* d = dst + (ph_off * 64 + pw) * LDK + c * 25 + ki * 5;
            #pragma unroll
            for (int kj = 0; kj < 5; ++kj)
                d[kj] = f2bf(src[kj]);
        }
    }
    // zero-pad cols 75..95 (read by the 3rd MFMA k-step)
    {
        int r = tid & 127, mat = tid >> 7;
        ushort* d = (mat ? Bsm : Asm) + r * LDK;
        #pragma unroll
        for (int c2 = KD; c2 < KP; ++c2) d[c2] = 0;
    }
    __syncthreads();

    int lane = tid & 63;
    int w  = tid >> 6;
    int wr = w >> 1, wc = w & 1;        // 2x2 wave grid, each wave 64x64 out
    int lrow = lane & 15;
    int lk   = (lane >> 4) * 8;

    f32x4 acc[4][4] = {};
    #pragma unroll
    for (int ks = 0; ks < 3; ++ks) {
        bf16x8 af[4], bfr[4];
        #pragma unroll
        for (int m = 0; m < 4; ++m)
            af[m] = *(const bf16x8*)&Asm[(wr * 64 + m * 16 + lrow) * LDK + ks * 32 + lk];
        #pragma unroll
        for (int n = 0; n < 4; ++n)
            bfr[n] = *(const bf16x8*)&Bsm[(wc * 64 + n * 16 + lrow) * LDK + ks * 32 + lk];
        #pragma unroll
        for (int m = 0; m < 4; ++m)
            #pragma unroll
            for (int n = 0; n < 4; ++n)
                acc[m][n] = __builtin_amdgcn_mfma_f32_16x16x32_bf16(af[m], bfr[n], acc[m][n], 0, 0, 0);
    }

    float inv = 1.0f / sqrtf(__uint_as_float(maxbits[b]));
    float* ob = out + (size_t)b * LP * LP;
    int orow0 = tr * 128 + wr * 64;     // logical GEMM rows (become cols after transpose)
    int ocol0 = tc * 128 + wc * 64;     // logical GEMM cols (become rows after transpose)
    #pragma unroll
    for (int m = 0; m < 4; ++m) {
        #pragma unroll
        for (int n = 0; n < 4; ++n) {
            // C/D layout: col=lane&15, row=(lane>>4)*4+reg. Store transposed:
            // output row = GEMM col, output col = GEMM row (4 consecutive -> float4).
            int trow = ocol0 + n * 16 + (lane & 15);
            int tcol = orow0 + m * 16 + (lane >> 4) * 4;
            f32x4 v;
            #pragma unroll
            for (int r = 0; r < 4; ++r) {
                float s = acc[m][n][r] * inv;
                v[r] = 1.0f / (1.0f + __expf(-s));
            }
            *(f32x4*)&ob[(size_t)trow * LP + tcol] = v;
        }
    }
}

extern "C" void kernel_launch(void* const* d_in, const int* in_sizes, int n_in,
                              void* d_out, int out_size, void* d_ws, size_t ws_size,
                              hipStream_t stream) {
    const float* x = (const float*)d_in[0];
    float* out = (float*)d_out;
    unsigned* maxbits = (unsigned*)d_ws;     // 4 words only — entire ws footprint

    hipMemsetAsync(maxbits, 0, NB * sizeof(unsigned), stream);   // capture-legal (memset node)
    norm_kernel<<<(NB * LP) / 4, 256, 0, stream>>>(x, maxbits);
    gemm_kernel<<<dim3(32, 32, NB), 256, 0, stream>>>(x, maxbits, out);
}